// Round 10
// baseline (359.647 us; speedup 1.0000x reference)
//
#include <hip/hip_runtime.h>
#include <stdint.h>

typedef __attribute__((ext_vector_type(8))) short bf16x8_t;
typedef __attribute__((ext_vector_type(4))) float f32x4_t;

#define GLOAD_LDS16(gp, lp) __builtin_amdgcn_global_load_lds( \
    (__attribute__((address_space(1))) void*)(void*)(gp),      \
    (__attribute__((address_space(3))) void*)(lp), 16, 0, 0)

#define CSR_STRIDE 96   // fixed slots/node (deg ~ Poisson(32); P(>96) ~ 1e-13, guarded)

__device__ __forceinline__ float bf2f(unsigned short u) {
  union { unsigned int i; float f; } c; c.i = ((unsigned int)u) << 16; return c.f;
}
__device__ __forceinline__ unsigned short f2bf(float f) {
  unsigned int x = __float_as_uint(f);
  unsigned int r = (x + 0x7fffu + ((x >> 16) & 1u)) >> 16;
  return (unsigned short)r;
}
__device__ __forceinline__ float fast_tanh(float x) {
  const float cx = fminf(fmaxf(x, -15.f), 15.f);
  const float e  = __expf(2.f * cx);
  return __fdividef(e - 1.f, e + 1.f);
}

// Same-XCD N-pair swizzle: both N-tiles of an M-tile share b%8 (same XCD) so the
// second N-tile hits the A-tile in that XCD's L2. b=(idx*16 + n*8 + xcd); bijective.
// mtPad8 = ceil(MT/8). Returns false for padding blocks.
__device__ __forceinline__ bool pair_map(int b, int mtPad8, int MT, int& m, int& n) {
  const int xcd = b & 7;
  const int idx = b >> 4;
  n = (b >> 3) & 1;
  m = xcd * mtPad8 + idx;
  return m < MT;
}

// ---------------- prep: x f32->bf16, weights f32->bf16, cursor zero, zero-row ----------------
__global__ void prep_kernel(const float* __restrict__ x, unsigned short* __restrict__ xh,
                            const float* __restrict__ Wg, const float* __restrict__ W1,
                            const float* __restrict__ W2, unsigned short* __restrict__ Wg_b,
                            unsigned short* __restrict__ W1_b, unsigned short* __restrict__ W2_b,
                            int* __restrict__ cursor, unsigned short* __restrict__ xws,
                            int n, int total) {
  const int gid = blockIdx.x * blockDim.x + threadIdx.x;
  const int i = gid * 4;
  if (i < total) {
    float4 v = *(const float4*)(x + i);
    int row = i >> 8, col = i & 255;
    ushort4 o;
    o.x = f2bf(v.x); o.y = f2bf(v.y); o.z = f2bf(v.z); o.w = f2bf(v.w);
    *(ushort4*)(xh + (size_t)row * 512 + col) = o;
  }
  if (gid < n) cursor[gid] = 0;
  if (gid < 256) xws[((size_t)(gid >> 5) * (n + 1) + n) * 32 + (gid & 31)] = 0;
  if (gid < 65536) {
    const float* src; unsigned short* dst; int off;
    if (i < 65536)              { src = Wg; dst = Wg_b; off = i; }
    else if (i < 65536 + 131072){ src = W1; dst = W1_b; off = i - 65536; }
    else                        { src = W2; dst = W2_b; off = i - (65536 + 131072); }
    float4 v = *(const float4*)(src + off);
    ushort4 o;
    o.x = f2bf(v.x); o.y = f2bf(v.y); o.z = f2bf(v.z); o.w = f2bf(v.w);
    *(ushort4*)(dst + off) = o;
  }
}

// ---------------- graph build: fixed-stride CSR, 2 edges/thread ----------------
__global__ void fill_kernel(const int* __restrict__ esrc, const int* __restrict__ edst,
                            int* __restrict__ cursor, unsigned short* __restrict__ csr16, int E) {
  int i = (blockIdx.x * blockDim.x + threadIdx.x) * 2;
  if (i < E) {
    const int2 s = *(const int2*)(esrc + i);
    const int2 d = *(const int2*)(edst + i);
    int pos0 = atomicAdd(&cursor[d.x], 1);
    if (pos0 < CSR_STRIDE) csr16[(size_t)d.x * CSR_STRIDE + pos0] = (unsigned short)s.x;
    if (i + 1 < E) {
      int pos1 = atomicAdd(&cursor[d.y], 1);
      if (pos1 < CSR_STRIDE) csr16[(size_t)d.y * CSR_STRIDE + pos1] = (unsigned short)s.y;
    }
  }
}

// ---------------- aggregation: XCD-sharded column slices, branchless 8x8 gather ----------------
// xws slice-major [8][N+1][32] bf16; slice s (3.2 MB) lives in XCD-s L2 (blockIdx.x&7 pin).
// Wave = 8 groups x 8 lanes; batch b: group g handles edge b*8+g; lane loads ushort4 (8 B)
// -> one gather instruction = 8 edges x 64 B = 512 B within the L2-resident slice.
// Empirical floor (r1..r9): ~32 64B-sectors/cycle chip-wide -> ~170 us for 12.8M sectors.
__global__ __launch_bounds__(256)
void agg_kernel(const unsigned short* __restrict__ xws, const unsigned short* __restrict__ csr16,
                const int* __restrict__ cursor, const float* __restrict__ bias,
                unsigned short* __restrict__ xh, int n) {
  const int tid   = threadIdx.x;
  const int wid   = tid >> 6;
  const int lane  = tid & 63;
  const int slice = blockIdx.x & 7;
  const int node  = (blockIdx.x >> 3) * 4 + wid;
  if (node >= n) return;
  const int g   = lane >> 3;        // edge group 0..7
  const int gl4 = (lane & 7) * 4;   // element offset of this lane's 4 cols
  const unsigned short* sbase = xws + (size_t)slice * (n + 1) * 32 + gl4;
  const int ZROW = n;

  float a0 = 0.f, a1 = 0.f, a2 = 0.f, a3 = 0.f;
  const int cnt = cursor[node];               // virtual self edge at index 'cnt'
  const unsigned short* crow = csr16 + (size_t)node * CSR_STRIDE;
  for (int base = 0; base <= cnt; base += 64) {
    const int il = base + lane;
    int pv = (int)crow[il];                   // may overrun row: masked below, +64 global pad
    pv = (il == cnt) ? node : pv;             // fold self-loop at prefetch
    const int rem = cnt - base;               // wave-uniform
#pragma unroll
    for (int b = 0; b < 8; ++b) {
      const int idx = b * 8 + g;
      const int sv  = __builtin_amdgcn_ds_bpermute(idx << 2, pv);
      const int src = (idx <= rem) ? sv : ZROW;
      const ushort4 v = *(const ushort4*)(sbase + ((unsigned)src << 5));
      a0 += bf2f(v.x); a1 += bf2f(v.y); a2 += bf2f(v.z); a3 += bf2f(v.w);
    }
  }
#pragma unroll
  for (int mask = 8; mask < 64; mask <<= 1) {
    a0 += __shfl_xor(a0, mask);
    a1 += __shfl_xor(a1, mask);
    a2 += __shfl_xor(a2, mask);
    a3 += __shfl_xor(a3, mask);
  }
  if (lane < 8) {
    const float di = rsqrtf((float)(cnt + 1));
    const int c0 = slice * 32 + gl4;
    ushort4 o;
    o.x = f2bf(fast_tanh(a0 * di + bias[c0 + 0]));
    o.y = f2bf(fast_tanh(a1 * di + bias[c0 + 1]));
    o.z = f2bf(fast_tanh(a2 * di + bias[c0 + 2]));
    o.w = f2bf(fast_tanh(a3 * di + bias[c0 + 3]));
    *(ushort4*)(xh + (size_t)node * 512 + 256 + c0) = o;
  }
}

// ---------------- GEMM1:  xws = dinv[row] * (xh[:,0:256] @ Wg^T), slice-major out ----------------
__global__ __launch_bounds__(256, 3)
void gemm1_kernel(const unsigned short* __restrict__ A, int lda,
                  const unsigned short* __restrict__ B,
                  const int* __restrict__ degc,
                  unsigned short* __restrict__ Cp, int M, int K, int mtPad8) {
  __shared__ __align__(16) unsigned short As[128 * 64];
  __shared__ __align__(16) unsigned short Bs[128 * 64];
  int mi, ni;
  if (!pair_map(blockIdx.x, mtPad8, (M + 127) / 128, mi, ni)) return;
  const int tid  = threadIdx.x;
  const int lane = tid & 63;
  const int wid  = tid >> 6;
  const int wm = wid & 1, wn = wid >> 1;
  const int tileM = mi * 128;
  const int tileN = ni * 128;

  const int rowInCh = lane >> 3;
  const int slot    = lane & 7;
  const int srcOff  = ((slot ^ rowInCh) * 8);

  f32x4_t acc[4][4];
#pragma unroll
  for (int m = 0; m < 4; ++m)
#pragma unroll
    for (int n = 0; n < 4; ++n) acc[m][n] = (f32x4_t){0.f, 0.f, 0.f, 0.f};

  for (int kt = 0; kt < K; kt += 64) {
#pragma unroll
    for (int cc = 0; cc < 4; ++cc) {
      const int c = wid * 4 + cc;
      const int r = c * 8 + rowInCh;
      const int rA = min(tileM + r, M - 1);
      GLOAD_LDS16(A + (size_t)rA * lda + (kt + srcOff), As + c * 512 + lane * 8);
      GLOAD_LDS16(B + (size_t)(tileN + r) * K + (kt + srcOff), Bs + c * 512 + lane * 8);
    }
    __syncthreads();
#pragma unroll
    for (int ks = 0; ks < 2; ++ks) {
      bf16x8_t af[4], bfr[4];
      const int ksl = ks * 4 + (lane >> 4);
#pragma unroll
      for (int m = 0; m < 4; ++m) {
        const int ra = wm * 64 + m * 16 + (lane & 15);
        af[m]  = *(const bf16x8_t*)(As + ra * 64 + ((ksl ^ (ra & 7)) * 8));
        const int rb = wn * 64 + m * 16 + (lane & 15);
        bfr[m] = *(const bf16x8_t*)(Bs + rb * 64 + ((ksl ^ (rb & 7)) * 8));
      }
#pragma unroll
      for (int m = 0; m < 4; ++m)
#pragma unroll
        for (int n = 0; n < 4; ++n)
          acc[m][n] = __builtin_amdgcn_mfma_f32_16x16x32_bf16(af[m], bfr[n], acc[m][n], 0, 0, 0);
    }
    __syncthreads();
  }

  const int colBase = tileN + wn * 64 + (lane & 15);
  const int rowBase = tileM + wm * 64 + ((lane >> 4) << 2);
#pragma unroll
  for (int m = 0; m < 4; ++m) {
    const int gr0 = rowBase + m * 16;
#pragma unroll
    for (int r = 0; r < 4; ++r) {
      const int gr = gr0 + r;
      if (gr < M) {
        const float rs = rsqrtf((float)(degc[gr] + 1));
#pragma unroll
        for (int n = 0; n < 4; ++n) {
          const int gc = colBase + n * 16;
          // slice-major: [slice=gc>>5][row][col=gc&31], row stride M+1
          Cp[((size_t)(gc >> 5) * (M + 1) + gr) * 32 + (gc & 31)] = f2bf(acc[m][n][r] * rs);
        }
      }
    }
  }
}

// ---------------- bf16 MFMA GEMM:  C[M,Nout] = A[M,K] @ B[Nout,K]^T ----------------
// OUT_MODE: 0 = f32 row-major, 1 = bf16 row-major
template<bool TANH, int OUT_MODE>
__global__ __launch_bounds__(256, 3)
void gemm_bt_kernel(const unsigned short* __restrict__ A, int lda,
                    const unsigned short* __restrict__ B,
                    const float* __restrict__ bias,
                    void* __restrict__ Cp, int ldc, int M, int K, int mtPad8) {
  __shared__ __align__(16) unsigned short As[128 * 64];
  __shared__ __align__(16) unsigned short Bs[128 * 64];
  int mi, ni;
  if (!pair_map(blockIdx.x, mtPad8, (M + 127) / 128, mi, ni)) return;
  const int tid  = threadIdx.x;
  const int lane = tid & 63;
  const int wid  = tid >> 6;
  const int wm = wid & 1, wn = wid >> 1;
  const int tileM = mi * 128;
  const int tileN = ni * 128;

  const int rowInCh = lane >> 3;
  const int slot    = lane & 7;
  const int srcOff  = ((slot ^ rowInCh) * 8);

  f32x4_t acc[4][4];
#pragma unroll
  for (int m = 0; m < 4; ++m)
#pragma unroll
    for (int n = 0; n < 4; ++n) acc[m][n] = (f32x4_t){0.f, 0.f, 0.f, 0.f};

  for (int kt = 0; kt < K; kt += 64) {
#pragma unroll
    for (int cc = 0; cc < 4; ++cc) {
      const int c = wid * 4 + cc;
      const int r = c * 8 + rowInCh;
      const int rA = min(tileM + r, M - 1);
      GLOAD_LDS16(A + (size_t)rA * lda + (kt + srcOff), As + c * 512 + lane * 8);
      GLOAD_LDS16(B + (size_t)(tileN + r) * K + (kt + srcOff), Bs + c * 512 + lane * 8);
    }
    __syncthreads();
#pragma unroll
    for (int ks = 0; ks < 2; ++ks) {
      bf16x8_t af[4], bfr[4];
      const int ksl = ks * 4 + (lane >> 4);
#pragma unroll
      for (int m = 0; m < 4; ++m) {
        const int ra = wm * 64 + m * 16 + (lane & 15);
        af[m]  = *(const bf16x8_t*)(As + ra * 64 + ((ksl ^ (ra & 7)) * 8));
        const int rb = wn * 64 + m * 16 + (lane & 15);
        bfr[m] = *(const bf16x8_t*)(Bs + rb * 64 + ((ksl ^ (rb & 7)) * 8));
      }
#pragma unroll
      for (int m = 0; m < 4; ++m)
#pragma unroll
        for (int n = 0; n < 4; ++n)
          acc[m][n] = __builtin_amdgcn_mfma_f32_16x16x32_bf16(af[m], bfr[n], acc[m][n], 0, 0, 0);
    }
    __syncthreads();
  }

  const int colBase = tileN + wn * 64 + (lane & 15);
  const int rowBase = tileM + wm * 64 + ((lane >> 4) << 2);
#pragma unroll
  for (int n = 0; n < 4; ++n) {
    const int gc = colBase + n * 16;
    const float bv = bias[gc];
#pragma unroll
    for (int m = 0; m < 4; ++m) {
      const int gr0 = rowBase + m * 16;
#pragma unroll
      for (int r = 0; r < 4; ++r) {
        const int gr = gr0 + r;
        if (gr < M) {
          float v = acc[m][n][r] + bv;
          if (TANH) v = fast_tanh(v);
          if (OUT_MODE == 0) ((float*)Cp)[(size_t)gr * ldc + gc] = v;
          else               ((unsigned short*)Cp)[(size_t)gr * ldc + gc] = f2bf(v);
        }
      }
    }
  }
}

// ---------------- launcher ----------------
extern "C" void kernel_launch(void* const* d_in, const int* in_sizes, int n_in,
                              void* d_out, int out_size, void* d_ws, size_t ws_size,
                              hipStream_t stream) {
  const float* x  = (const float*)d_in[0];
  const int*   ei = (const int*)d_in[1];
  const float* Wg = (const float*)d_in[3];
  const float* bg = (const float*)d_in[4];
  const float* W1 = (const float*)d_in[5];
  const float* b1 = (const float*)d_in[6];
  const float* W2 = (const float*)d_in[7];
  const float* b2 = (const float*)d_in[8];
  float* out = (float*)d_out;

  const int N = in_sizes[0] / 256;
  const int E = in_sizes[1] / 2;
  const int* esrc = ei;
  const int* edst = ei + E;

  // xh = [x_bf16 | x1_bf16]  [N,512] bf16 aliases d_out (consumed before GEMM3 writes)
  unsigned short* xh = (unsigned short*)d_out;

  uint8_t* p = (uint8_t*)d_ws;
  auto alloc = [&](size_t bytes) { uint8_t* q = p; p += (bytes + 255) & ~(size_t)255; return q; };
  unsigned short* xws   = (unsigned short*)alloc((size_t)8 * (N + 1) * 32 * 2); // [8][N+1][32]
  unsigned short* h2    = (unsigned short*)alloc((size_t)N * 256 * 2);
  unsigned short* Wg_b  = (unsigned short*)alloc(256 * 256 * 2);
  unsigned short* W1_b  = (unsigned short*)alloc(256 * 512 * 2);
  unsigned short* W2_b  = (unsigned short*)alloc(256 * 256 * 2);
  int*            cursor= (int*)alloc((size_t)N * 4);
  unsigned short* csr16 = (unsigned short*)alloc(((size_t)N * CSR_STRIDE + 64) * 2);
  (void)ws_size; (void)n_in;

  prep_kernel<<<(N * 256 / 4 + 255) / 256, 256, 0, stream>>>(
      x, xh, Wg, W1, W2, Wg_b, W1_b, W2_b, cursor, xws, N, N * 256);
  fill_kernel<<<(E / 2 + 255) / 256, 256, 0, stream>>>(esrc, edst, cursor, csr16, E);

  const int MT = (N + 127) / 128;            // 391
  const int mtPad8 = (MT + 7) / 8;           // 49
  const int gemm_grid = mtPad8 * 8 * 2;      // 784 blocks, same-XCD N-pairs
  gemm1_kernel<<<gemm_grid, 256, 0, stream>>>(xh, 512, Wg_b, cursor, xws, N, 256, mtPad8);
  agg_kernel<<<8 * ((N + 3) / 4), 256, 0, stream>>>(xws, csr16, cursor, bg, xh, N);
  // GEMM2: h2 = tanh([x|x1] @ W1^T + b1), bf16 out
  gemm_bt_kernel<true, 1><<<gemm_grid, 256, 0, stream>>>(xh, 512, W1_b, b1, h2, 256, N, 512, mtPad8);
  // GEMM3: out = tanh(h2 @ W2^T + b2), f32 out
  gemm_bt_kernel<true, 0><<<gemm_grid, 256, 0, stream>>>(h2, 256, W2_b, b2, out, 256, N, 256, mtPad8);
}

// Round 11
// 341.889 us; speedup vs baseline: 1.0519x; 1.0519x over previous
//
#include <hip/hip_runtime.h>
#include <stdint.h>

typedef __attribute__((ext_vector_type(8))) short bf16x8_t;
typedef __attribute__((ext_vector_type(4))) float f32x4_t;

#define GLOAD_LDS16(gp, lp) __builtin_amdgcn_global_load_lds( \
    (__attribute__((address_space(1))) void*)(void*)(gp),      \
    (__attribute__((address_space(3))) void*)(lp), 16, 0, 0)

#define CSR_STRIDE 96   // fixed slots/node (deg ~ Poisson(32); P(>96) ~ 1e-13, guarded)

__device__ __forceinline__ float bf2f(unsigned short u) {
  union { unsigned int i; float f; } c; c.i = ((unsigned int)u) << 16; return c.f;
}
__device__ __forceinline__ unsigned short f2bf(float f) {
  unsigned int x = __float_as_uint(f);
  unsigned int r = (x + 0x7fffu + ((x >> 16) & 1u)) >> 16;
  return (unsigned short)r;
}
__device__ __forceinline__ float fast_tanh(float x) {
  const float cx = fminf(fmaxf(x, -15.f), 15.f);
  const float e  = __expf(2.f * cx);
  return __fdividef(e - 1.f, e + 1.f);
}

// ---------------- prep: x f32->bf16, weights f32->bf16, cursor zero, zero-row ----------------
__global__ void prep_kernel(const float* __restrict__ x, unsigned short* __restrict__ xh,
                            const float* __restrict__ Wg, const float* __restrict__ W1,
                            const float* __restrict__ W2, unsigned short* __restrict__ Wg_b,
                            unsigned short* __restrict__ W1_b, unsigned short* __restrict__ W2_b,
                            int* __restrict__ cursor, unsigned short* __restrict__ xws,
                            int n, int total) {
  const int gid = blockIdx.x * blockDim.x + threadIdx.x;
  const int i = gid * 4;
  if (i < total) {
    float4 v = *(const float4*)(x + i);
    int row = i >> 8, col = i & 255;
    ushort4 o;
    o.x = f2bf(v.x); o.y = f2bf(v.y); o.z = f2bf(v.z); o.w = f2bf(v.w);
    *(ushort4*)(xh + (size_t)row * 512 + col) = o;
  }
  if (gid < n) cursor[gid] = 0;
  if (gid < 256) xws[((size_t)(gid >> 5) * (n + 1) + n) * 32 + (gid & 31)] = 0;
  if (gid < 65536) {
    const float* src; unsigned short* dst; int off;
    if (i < 65536)              { src = Wg; dst = Wg_b; off = i; }
    else if (i < 65536 + 131072){ src = W1; dst = W1_b; off = i - 65536; }
    else                        { src = W2; dst = W2_b; off = i - (65536 + 131072); }
    float4 v = *(const float4*)(src + off);
    ushort4 o;
    o.x = f2bf(v.x); o.y = f2bf(v.y); o.z = f2bf(v.z); o.w = f2bf(v.w);
    *(ushort4*)(dst + off) = o;
  }
}

// ---------------- graph build: fixed-stride CSR ----------------
__global__ void fill_kernel(const int* __restrict__ esrc, const int* __restrict__ edst,
                            int* __restrict__ cursor, unsigned short* __restrict__ csr16, int E) {
  int i = blockIdx.x * blockDim.x + threadIdx.x;
  if (i < E) {
    int d = edst[i];
    int pos = atomicAdd(&cursor[d], 1);
    if (pos < CSR_STRIDE) csr16[(size_t)d * CSR_STRIDE + pos] = (unsigned short)esrc[i];
  }
}

// ---------------- aggregation: XCD-sharded column slices, branchless 8x8 gather ----------------
// xws slice-major [8][N+1][32] bf16; slice s (3.2 MB) lives in XCD-s L2 (blockIdx.x&7 pin).
// Wave = 8 groups x 8 lanes; batch b: group g handles edge b*8+g; lane loads ushort4 (8 B)
// -> one gather instruction = 8 edges x 64 B = 512 B within the L2-resident slice.
// Empirical floor (r1..r10): ~32 64B-sectors/cycle chip-wide -> ~170 us for 12.8M sectors.
__global__ __launch_bounds__(256)
void agg_kernel(const unsigned short* __restrict__ xws, const unsigned short* __restrict__ csr16,
                const int* __restrict__ cursor, const float* __restrict__ bias,
                unsigned short* __restrict__ xh, int n) {
  const int tid   = threadIdx.x;
  const int wid   = tid >> 6;
  const int lane  = tid & 63;
  const int slice = blockIdx.x & 7;
  const int node  = (blockIdx.x >> 3) * 4 + wid;
  if (node >= n) return;
  const int g   = lane >> 3;        // edge group 0..7
  const int gl4 = (lane & 7) * 4;   // element offset of this lane's 4 cols
  const unsigned short* sbase = xws + (size_t)slice * (n + 1) * 32 + gl4;
  const int ZROW = n;

  float a0 = 0.f, a1 = 0.f, a2 = 0.f, a3 = 0.f;
  const int cnt = cursor[node];               // virtual self edge at index 'cnt'
  const unsigned short* crow = csr16 + (size_t)node * CSR_STRIDE;
  for (int base = 0; base <= cnt; base += 64) {
    const int il = base + lane;
    int pv = (int)crow[il];                   // may overrun row: masked below, +64 global pad
    pv = (il == cnt) ? node : pv;             // fold self-loop at prefetch
    const int rem = cnt - base;               // wave-uniform
#pragma unroll
    for (int b = 0; b < 8; ++b) {
      const int idx = b * 8 + g;
      const int sv  = __builtin_amdgcn_ds_bpermute(idx << 2, pv);
      const int src = (idx <= rem) ? sv : ZROW;
      const ushort4 v = *(const ushort4*)(sbase + ((unsigned)src << 5));
      a0 += bf2f(v.x); a1 += bf2f(v.y); a2 += bf2f(v.z); a3 += bf2f(v.w);
    }
  }
#pragma unroll
  for (int mask = 8; mask < 64; mask <<= 1) {
    a0 += __shfl_xor(a0, mask);
    a1 += __shfl_xor(a1, mask);
    a2 += __shfl_xor(a2, mask);
    a3 += __shfl_xor(a3, mask);
  }
  if (lane < 8) {
    const float di = rsqrtf((float)(cnt + 1));
    const int c0 = slice * 32 + gl4;
    ushort4 o;
    o.x = f2bf(fast_tanh(a0 * di + bias[c0 + 0]));
    o.y = f2bf(fast_tanh(a1 * di + bias[c0 + 1]));
    o.z = f2bf(fast_tanh(a2 * di + bias[c0 + 2]));
    o.w = f2bf(fast_tanh(a3 * di + bias[c0 + 3]));
    *(ushort4*)(xh + (size_t)node * 512 + 256 + c0) = o;
  }
}

// ---------------- full-width bf16 MFMA GEMM: C[M,256] = A[M,K] @ B[256,K]^T ----------------
// 128x256 tile (whole output width per block): A staged ONCE per block (vs twice with
// (MT,2) grids), 128 MFMAs per wave per K-step (2x barrier amortization), 391 blocks all
// co-resident in one occupancy wave. LDS 48 KB -> 2 blocks/CU.
// OUT_MODE: 0 = f32 row-major, 1 = bf16 row-major, 2 = bf16 slice-major [8][M+1][32],
//           row-scaled by rsqrt(degc+1).
template<bool TANH, int OUT_MODE>
__global__ __launch_bounds__(256, 2)
void gemm_w_kernel(const unsigned short* __restrict__ A, int lda,
                   const unsigned short* __restrict__ B,
                   const float* __restrict__ bias,
                   const int* __restrict__ degc,
                   void* __restrict__ Cp, int M, int K) {
  __shared__ __align__(16) unsigned short As[128 * 64];
  __shared__ __align__(16) unsigned short Bs[256 * 64];
  const int tid  = threadIdx.x;
  const int lane = tid & 63;
  const int wid  = tid >> 6;
  const int wm = wid & 1, wn = wid >> 1;      // wave: 64 rows x 128 cols
  const int tileM = blockIdx.x * 128;

  const int rowInCh = lane >> 3;
  const int slot    = lane & 7;
  const int srcOff  = ((slot ^ rowInCh) * 8);

  f32x4_t acc[4][8];
#pragma unroll
  for (int m = 0; m < 4; ++m)
#pragma unroll
    for (int n = 0; n < 8; ++n) acc[m][n] = (f32x4_t){0.f, 0.f, 0.f, 0.f};

  for (int kt = 0; kt < K; kt += 64) {
#pragma unroll
    for (int cc = 0; cc < 4; ++cc) {          // A: 16 chunks x 8 rows = 128
      const int c = wid * 4 + cc;
      const int r = c * 8 + rowInCh;
      const int rA = min(tileM + r, M - 1);
      GLOAD_LDS16(A + (size_t)rA * lda + (kt + srcOff), As + c * 512 + lane * 8);
    }
#pragma unroll
    for (int cc = 0; cc < 8; ++cc) {          // B: 32 chunks x 8 rows = 256
      const int c = wid * 8 + cc;
      const int r = c * 8 + rowInCh;
      GLOAD_LDS16(B + (size_t)r * K + (kt + srcOff), Bs + c * 512 + lane * 8);
    }
    __syncthreads();
#pragma unroll
    for (int ks = 0; ks < 2; ++ks) {
      bf16x8_t af[4], bfr[8];
      const int ksl = ks * 4 + (lane >> 4);
#pragma unroll
      for (int m = 0; m < 4; ++m) {
        const int ra = wm * 64 + m * 16 + (lane & 15);
        af[m] = *(const bf16x8_t*)(As + ra * 64 + ((ksl ^ (ra & 7)) * 8));
      }
#pragma unroll
      for (int n = 0; n < 8; ++n) {
        const int rb = wn * 128 + n * 16 + (lane & 15);
        bfr[n] = *(const bf16x8_t*)(Bs + rb * 64 + ((ksl ^ (rb & 7)) * 8));
      }
#pragma unroll
      for (int m = 0; m < 4; ++m)
#pragma unroll
        for (int n = 0; n < 8; ++n)
          acc[m][n] = __builtin_amdgcn_mfma_f32_16x16x32_bf16(af[m], bfr[n], acc[m][n], 0, 0, 0);
    }
    __syncthreads();
  }

  const int colBase = wn * 128 + (lane & 15);
  const int rowBase = tileM + wm * 64 + ((lane >> 4) << 2);
#pragma unroll
  for (int m = 0; m < 4; ++m) {
    const int gr0 = rowBase + m * 16;
#pragma unroll
    for (int r = 0; r < 4; ++r) {
      const int gr = gr0 + r;
      if (gr < M) {
        float rs = 1.f;
        if (OUT_MODE == 2) rs = rsqrtf((float)(degc[gr] + 1));
#pragma unroll
        for (int n = 0; n < 8; ++n) {
          const int gc = colBase + n * 16;
          float v = acc[m][n][r];
          if (OUT_MODE == 2) {
            ((unsigned short*)Cp)[((size_t)(gc >> 5) * (M + 1) + gr) * 32 + (gc & 31)] = f2bf(v * rs);
          } else {
            v += bias[gc];
            if (TANH) v = fast_tanh(v);
            if (OUT_MODE == 0) ((float*)Cp)[(size_t)gr * 256 + gc] = v;
            else               ((unsigned short*)Cp)[(size_t)gr * 256 + gc] = f2bf(v);
          }
        }
      }
    }
  }
}

// ---------------- launcher ----------------
extern "C" void kernel_launch(void* const* d_in, const int* in_sizes, int n_in,
                              void* d_out, int out_size, void* d_ws, size_t ws_size,
                              hipStream_t stream) {
  const float* x  = (const float*)d_in[0];
  const int*   ei = (const int*)d_in[1];
  const float* Wg = (const float*)d_in[3];
  const float* bg = (const float*)d_in[4];
  const float* W1 = (const float*)d_in[5];
  const float* b1 = (const float*)d_in[6];
  const float* W2 = (const float*)d_in[7];
  const float* b2 = (const float*)d_in[8];
  float* out = (float*)d_out;

  const int N = in_sizes[0] / 256;
  const int E = in_sizes[1] / 2;
  const int* esrc = ei;
  const int* edst = ei + E;

  // xh = [x_bf16 | x1_bf16]  [N,512] bf16 aliases d_out (consumed before GEMM3 writes)
  unsigned short* xh = (unsigned short*)d_out;

  uint8_t* p = (uint8_t*)d_ws;
  auto alloc = [&](size_t bytes) { uint8_t* q = p; p += (bytes + 255) & ~(size_t)255; return q; };
  unsigned short* xws   = (unsigned short*)alloc((size_t)8 * (N + 1) * 32 * 2); // [8][N+1][32]
  unsigned short* h2    = (unsigned short*)alloc((size_t)N * 256 * 2);
  unsigned short* Wg_b  = (unsigned short*)alloc(256 * 256 * 2);
  unsigned short* W1_b  = (unsigned short*)alloc(256 * 512 * 2);
  unsigned short* W2_b  = (unsigned short*)alloc(256 * 256 * 2);
  int*            cursor= (int*)alloc((size_t)N * 4);
  unsigned short* csr16 = (unsigned short*)alloc(((size_t)N * CSR_STRIDE + 64) * 2);
  (void)ws_size; (void)n_in;

  prep_kernel<<<(N * 256 / 4 + 255) / 256, 256, 0, stream>>>(
      x, xh, Wg, W1, W2, Wg_b, W1_b, W2_b, cursor, xws, N, N * 256);
  fill_kernel<<<(E + 255) / 256, 256, 0, stream>>>(esrc, edst, cursor, csr16, E);

  const int MT = (N + 127) / 128;   // 391 blocks, all co-resident at 2 blocks/CU
  // GEMM1: xws = rsqrt(deg+1)[row] * (xh[:,0:256] @ Wg^T), slice-major bf16 out
  gemm_w_kernel<false, 2><<<MT, 256, 0, stream>>>(xh, 512, Wg_b, nullptr, cursor, xws, N, 256);
  // aggregate + bias + tanh -> xh[:, 256:512]
  agg_kernel<<<8 * ((N + 3) / 4), 256, 0, stream>>>(xws, csr16, cursor, bg, xh, N);
  // GEMM2: h2 = tanh([x|x1] @ W1^T + b1), bf16 out
  gemm_w_kernel<true, 1><<<MT, 256, 0, stream>>>(xh, 512, W1_b, b1, nullptr, h2, N, 512);
  // GEMM3: out = tanh(h2 @ W2^T + b2), f32 out
  gemm_w_kernel<true, 0><<<MT, 256, 0, stream>>>(h2, 256, W2_b, b2, nullptr, out, N, 256);
}